// Round 4
// baseline (1314.960 us; speedup 1.0000x reference)
//
#include <hip/hip_runtime.h>
#include <math.h>

#define ALPHA 0.3f

constexpr int B  = 32;
constexpr int N  = 100;
constexpr int NF = 128;
constexpr int L  = 3;
constexpr int NN = N * N;            // 10000
constexpr int NPAIR = B * NN;        // 320000
constexpr int PT = 32;               // pairs per block in the fused MFMA MLP

typedef __attribute__((ext_vector_type(8))) short short8;
typedef __attribute__((ext_vector_type(4))) float f32x4;

__device__ __forceinline__ unsigned short f2bf(float x) {
    union { float f; unsigned u; } v; v.f = x;
    unsigned r = v.u + 0x7FFF + ((v.u >> 16) & 1);  // RNE
    return (unsigned short)(r >> 16);
}
__device__ __forceinline__ float bf2f(unsigned short h) {
    union { unsigned u; float f; } v; v.u = ((unsigned)h) << 16;
    return v.f;
}

// ---------------------------------------------------------------------------
// Weight prep: Wt[l][c][k] = W[l][k][c] * S[l][c]  (bf16, S folded)
// ---------------------------------------------------------------------------
__global__ void k_wprep(const float* __restrict__ W, const float* __restrict__ S,
                        unsigned short* __restrict__ Wt, int K, int C) {
    int idx = blockIdx.x * blockDim.x + threadIdx.x;
    int per = K * C;
    if (idx >= L * per) return;
    int l = idx / per, r = idx - l * per;
    int c = r / K, k = r - c * K;
    float v = W[(size_t)l * per + (size_t)k * C + c] * S[l * C + c];
    Wt[idx] = f2bf(v);
}

// ---------------------------------------------------------------------------
// Kernel A: per (b,m) row — L1-normalize masked edge rows, aggregate node
// features, and build x = [nf | aggr0 | aggr1]  ([B,N,3*NF])
// ---------------------------------------------------------------------------
__global__ void k_aggr_x(const float* __restrict__ nf,
                         const float* __restrict__ ef,
                         float* __restrict__ x) {
    const int b = blockIdx.x / N;
    const int m = blockIdx.x - b * N;
    const int t = threadIdx.x;  // 128 threads

    __shared__ float w0[128], w1[128];

    float e0 = 0.f, e1 = 0.f;
    if (t < N) {
        e0 = ef[((size_t)(b * 2 + 0) * N + m) * N + t];
        e1 = ef[((size_t)(b * 2 + 1) * N + m) * N + t];
        if (t == m) { e0 = 0.f; e1 = 0.f; }
    }
    w0[t] = fabsf(e0);
    w1[t] = fabsf(e1);
    __syncthreads();
    for (int s = 64; s > 0; s >>= 1) {
        if (t < s) { w0[t] += w0[t + s]; w1[t] += w1[t + s]; }
        __syncthreads();
    }
    const float s0 = w0[0];
    const float s1 = w1[0];
    __syncthreads();
    w0[t] = (s0 == 0.f) ? 0.f : e0 / s0;
    w1[t] = (s1 == 0.f) ? 0.f : e1 / s1;
    __syncthreads();

    const float* nfb = nf + (size_t)b * N * NF;
    float a0 = 0.f, a1 = 0.f;
#pragma unroll 4
    for (int n = 0; n < N; ++n) {
        const float v = nfb[(size_t)n * NF + t];
        a0 = fmaf(w0[n], v, a0);
        a1 = fmaf(w1[n], v, a1);
    }
    float* xr = x + (size_t)(b * N + m) * (3 * NF);
    xr[t]          = nfb[(size_t)m * NF + t];
    xr[NF + t]     = a0;
    xr[2 * NF + t] = a1;
}

// ---------------------------------------------------------------------------
// Kernel B: multi-row affine GEMM (f32): out = leaky((in@W)*S+Bb)
// ---------------------------------------------------------------------------
template <int K, int COUT, int R>
__global__ void k_affine_mr(const float* __restrict__ in,
                            const float* __restrict__ W,
                            const float* __restrict__ S,
                            const float* __restrict__ Bb,
                            float* __restrict__ out) {
    __shared__ float xr[R][K];
    const int r0 = blockIdx.x * R;
    const int c = threadIdx.x;  // COUT threads
    for (int idx = c; idx < R * K; idx += COUT) {
        const int rr = idx / K, kk = idx - rr * K;
        xr[rr][kk] = in[(size_t)(r0 + rr) * K + kk];
    }
    __syncthreads();
    float acc[R];
#pragma unroll
    for (int r = 0; r < R; ++r) acc[r] = 0.f;
    const float* Wc = W + c;
#pragma unroll 4
    for (int k = 0; k < K; ++k) {
        const float wv = Wc[(size_t)k * COUT];
#pragma unroll
        for (int r = 0; r < R; ++r) acc[r] = fmaf(xr[r][k], wv, acc[r]);
    }
    const float sc = S[c], bb = Bb[c];
#pragma unroll
    for (int r = 0; r < R; ++r) {
        float v = acc[r] * sc + bb;
        out[(size_t)(r0 + r) * COUT + c] = (v >= 0.f) ? v : ALPHA * v;
    }
}

// ---------------------------------------------------------------------------
// MFMA MLP layer: out[p,c] = leaky((in[p,:] @ W')[c] + Bb[c]), bf16 in/out
// in/out are swizzled LDS tiles: byte = p*(K*2) + ((col*2) ^ ((p&15)<<4))
// Wt is [COUT][K] bf16 in global (S pre-folded).
// 8 waves: wave owns cols [wave*NT*16 ...), MT M-tiles (PT pairs).
// ---------------------------------------------------------------------------
template <int K, int COUT, int NT, int MT>
__device__ __forceinline__ void layer_mfma(const unsigned short* in,
                                           unsigned short* out,
                                           const unsigned short* __restrict__ Wt,
                                           const float* __restrict__ Bb,
                                           int lane, int wave) {
    const int r16 = lane & 15, g = lane >> 4;
    f32x4 acc[MT][NT];
#pragma unroll
    for (int m = 0; m < MT; ++m)
#pragma unroll
        for (int n = 0; n < NT; ++n) acc[m][n] = (f32x4){0.f, 0.f, 0.f, 0.f};

    const int cbase = wave * NT * 16;
#pragma unroll
    for (int ks = 0; ks < K / 32; ++ks) {
        short8 av[MT];
#pragma unroll
        for (int m = 0; m < MT; ++m) {
            const int p = m * 16 + r16;
            const int byte = (ks * 64 + g * 16) ^ ((p & 15) << 4);
            av[m] = *(const short8*)((const char*)in + p * (K * 2) + byte);
        }
        short8 bv[NT];
#pragma unroll
        for (int n = 0; n < NT; ++n) {
            const int c = cbase + n * 16 + r16;
            bv[n] = *(const short8*)(Wt + (size_t)c * K + ks * 32 + g * 8);
        }
#pragma unroll
        for (int m = 0; m < MT; ++m)
#pragma unroll
            for (int n = 0; n < NT; ++n)
                acc[m][n] = __builtin_amdgcn_mfma_f32_16x16x32_bf16(
                    av[m], bv[n], acc[m][n], 0, 0, 0);
    }
#pragma unroll
    for (int n = 0; n < NT; ++n) {
        const int c = cbase + n * 16 + r16;
        const float bias = Bb[c];
#pragma unroll
        for (int m = 0; m < MT; ++m) {
#pragma unroll
            for (int r = 0; r < 4; ++r) {
                const int p = m * 16 + g * 4 + r;
                float v = acc[m][n][r] + bias;
                v = (v >= 0.f) ? v : ALPHA * v;
                const int byte = (c * 2) ^ ((p & 15) << 4);
                *(unsigned short*)((char*)out + p * (COUT * 2) + byte) = f2bf(v);
            }
        }
    }
}

// ---------------------------------------------------------------------------
// Kernel C: fused pairwise-difference MLP (bf16 MFMA) -> sim[b,i,j]
// 512 threads = 8 waves per block, 32 pairs per block; 32 KiB LDS ->
// 4 blocks/CU (32 waves/CU) at VGPR<=64.
// ---------------------------------------------------------------------------
__global__ __launch_bounds__(512, 8) void k_pair_mlp_mfma(
    const float* __restrict__ nf,
    const unsigned short* __restrict__ W0t, const float* __restrict__ Bb0,
    const unsigned short* __restrict__ W1t, const float* __restrict__ Bb1,
    const unsigned short* __restrict__ W2t, const float* __restrict__ Bb2,
    const unsigned short* __restrict__ W3t, const float* __restrict__ Bb3,
    const float* __restrict__ Wout, const float* __restrict__ boutp,
    float* __restrict__ sim) {
    __shared__ unsigned short bufA[PT * 256];  // 16 KiB
    __shared__ unsigned short bufB[PT * 256];  // 16 KiB
    const int t = threadIdx.x;
    const int lane = t & 63, wave = t >> 6;
    const int tile0 = blockIdx.x * PT;

    // Stage h0 = |nf_i - nf_j| into bufA as swizzled bf16 (row width 128ch)
    {
        const int p = t >> 4, q = t & 15;   // pair 0..31, 8-ch chunk 0..15
        const int P = tile0 + p;
        const int b = P / NN;
        int r = P - b * NN;
        const int i = r / N, j = r - i * N;
        const float4* fi = (const float4*)(nf + ((size_t)(b * N + i)) * NF + q * 8);
        const float4* fj = (const float4*)(nf + ((size_t)(b * N + j)) * NF + q * 8);
        const float4 a0 = fi[0], a1 = fi[1];
        const float4 c0 = fj[0], c1 = fj[1];
        short8 o;
        o[0] = (short)f2bf(fabsf(a0.x - c0.x));
        o[1] = (short)f2bf(fabsf(a0.y - c0.y));
        o[2] = (short)f2bf(fabsf(a0.z - c0.z));
        o[3] = (short)f2bf(fabsf(a0.w - c0.w));
        o[4] = (short)f2bf(fabsf(a1.x - c1.x));
        o[5] = (short)f2bf(fabsf(a1.y - c1.y));
        o[6] = (short)f2bf(fabsf(a1.z - c1.z));
        o[7] = (short)f2bf(fabsf(a1.w - c1.w));
        const int byte = (q * 16) ^ ((p & 15) << 4);
        *(short8*)((char*)bufA + p * 256 + byte) = o;
    }
    __syncthreads();
    layer_mfma<128, 256, 2, 2>(bufA, bufB, W0t, Bb0, lane, wave);
    __syncthreads();
    layer_mfma<256, 256, 2, 2>(bufB, bufA, W1t, Bb1, lane, wave);
    __syncthreads();
    layer_mfma<256, 128, 1, 2>(bufA, bufB, W2t, Bb2, lane, wave);
    __syncthreads();
    layer_mfma<128, 128, 1, 2>(bufB, bufA, W3t, Bb3, lane, wave);
    __syncthreads();

    // sim = sigmoid(h @ Wout + bout), h = bufA (swizzled bf16, 128 ch)
    {
        const int p = t >> 4, q = t & 15;
        const int byte = (q * 16) ^ ((p & 15) << 4);
        const short8 hv = *(const short8*)((const char*)bufA + p * 256 + byte);
        const float* wp = Wout + q * 8;
        float acc = 0.f;
#pragma unroll
        for (int d = 0; d < 8; ++d)
            acc = fmaf(bf2f((unsigned short)hv[d]), wp[d], acc);
        acc += __shfl_xor(acc, 1);
        acc += __shfl_xor(acc, 2);
        acc += __shfl_xor(acc, 4);
        acc += __shfl_xor(acc, 8);
        if (q == 0) {
            const float v = acc + boutp[0];
            sim[tile0 + p] = 1.f / (1.f + expf(-v));
        }
    }
}

// ---------------------------------------------------------------------------
// Kernel D: edge update given sim (row-local; safe in place)
// ---------------------------------------------------------------------------
__global__ void k_edge_update(const float* __restrict__ ef_in,
                              const float* __restrict__ sim,
                              float* __restrict__ ef_out) {
    const int b = blockIdx.x / N;
    const int i = blockIdx.x - b * N;
    const int t = threadIdx.x;  // 128 threads

    __shared__ float r0[128], r1[128], r2[128], r3[128];

    float e0 = 0.f, e1 = 0.f, s = 0.f;
    if (t < N) {
        e0 = ef_in[((size_t)(b * 2 + 0) * N + i) * N + t];
        e1 = ef_in[((size_t)(b * 2 + 1) * N + i) * N + t];
        if (t == i) { e0 = 0.f; e1 = 0.f; }
        s = sim[(size_t)(b * N + i) * N + t];
    }
    float f0 = e0 * s;
    float f1 = e1 * (1.f - s);
    r0[t] = e0; r1[t] = e1; r2[t] = fabsf(f0); r3[t] = fabsf(f1);
    __syncthreads();
    for (int st = 64; st > 0; st >>= 1) {
        if (t < st) {
            r0[t] += r0[t + st];
            r1[t] += r1[t + st];
            r2[t] += r2[t + st];
            r3[t] += r3[t + st];
        }
        __syncthreads();
    }
    const float m0 = r0[0], m1 = r1[0], n0 = r2[0], n1 = r3[0];
    if (t < N) {
        f0 = (n0 == 0.f) ? 0.f : (f0 / n0) * m0;
        f1 = (n1 == 0.f) ? 0.f : (f1 / n1) * m1;
        if (t == i) f0 += 1.f;
        f0 += 1e-6f;
        f1 += 1e-6f;
        const float inv = 1.f / (f0 + f1);
        ef_out[((size_t)(b * 2 + 0) * N + i) * N + t] = f0 * inv;
        ef_out[((size_t)(b * 2 + 1) * N + i) * N + t] = f1 * inv;
    }
}

// ---------------------------------------------------------------------------
extern "C" void kernel_launch(void* const* d_in, const int* in_sizes, int n_in,
                              void* d_out, int out_size, void* d_ws, size_t ws_size,
                              hipStream_t stream) {
    (void)in_sizes; (void)n_in; (void)out_size; (void)ws_size;

    const float* node_feat = (const float*)d_in[0];
    const float* edge_feat = (const float*)d_in[1];
    const float* nW0 = (const float*)d_in[2];
    const float* nS0 = (const float*)d_in[3];
    const float* nB0 = (const float*)d_in[4];
    const float* nW1 = (const float*)d_in[5];
    const float* nS1 = (const float*)d_in[6];
    const float* nB1 = (const float*)d_in[7];
    const float* eW0 = (const float*)d_in[8];
    const float* eS0 = (const float*)d_in[9];
    const float* eB0 = (const float*)d_in[10];
    const float* eW1 = (const float*)d_in[11];
    const float* eS1 = (const float*)d_in[12];
    const float* eB1 = (const float*)d_in[13];
    const float* eW2 = (const float*)d_in[14];
    const float* eS2 = (const float*)d_in[15];
    const float* eB2 = (const float*)d_in[16];
    const float* eW3 = (const float*)d_in[17];
    const float* eS3 = (const float*)d_in[18];
    const float* eB3 = (const float*)d_in[19];
    const float* eWout = (const float*)d_in[20];
    const float* eBout = (const float*)d_in[21];

    float* ws     = (float*)d_ws;
    float* nf_a   = ws;                               // B*N*NF
    float* nf_b   = nf_a + (size_t)B * N * NF;        // B*N*NF
    float* xbuf   = nf_b + (size_t)B * N * NF;        // B*N*3*NF
    float* hbuf   = xbuf + (size_t)B * N * 3 * NF;    // B*N*2*NF
    float* ef_ws  = hbuf + (size_t)B * N * 2 * NF;    // B*2*N*N
    float* simbuf = ef_ws + (size_t)B * 2 * N * N;    // B*N*N
    unsigned short* w0t = (unsigned short*)(simbuf + (size_t)B * N * N);
    unsigned short* w1t = w0t + (size_t)L * 256 * 128;   // [L][256][128]
    unsigned short* w2t = w1t + (size_t)L * 256 * 256;   // [L][256][256]
    unsigned short* w3t = w2t + (size_t)L * 128 * 256;   // [L][128][256]
    // w3t: [L][128][128]; total ws ~16.2 MB

    // --- weight prep (bf16, transposed, S folded) ---
    k_wprep<<<(L * 128 * 256 + 255) / 256, 256, 0, stream>>>(eW0, eS0, w0t, 128, 256);
    k_wprep<<<(L * 256 * 256 + 255) / 256, 256, 0, stream>>>(eW1, eS1, w1t, 256, 256);
    k_wprep<<<(L * 256 * 128 + 255) / 256, 256, 0, stream>>>(eW2, eS2, w2t, 256, 128);
    k_wprep<<<(L * 128 * 128 + 255) / 256, 256, 0, stream>>>(eW3, eS3, w3t, 128, 128);

    const float* nf_cur = node_feat;
    const float* ef_cur = edge_feat;
    float* nf_next_buf[3] = {nf_a, nf_b, nf_a};

    for (int l = 0; l < L; ++l) {
        // ---- node update (f32) ----
        k_aggr_x<<<B * N, 128, 0, stream>>>(nf_cur, ef_cur, xbuf);
        k_affine_mr<3 * NF, 2 * NF, 8><<<B * N / 8, 2 * NF, 0, stream>>>(
            xbuf, nW0 + (size_t)l * 3 * NF * 2 * NF, nS0 + l * 2 * NF, nB0 + l * 2 * NF, hbuf);
        k_affine_mr<2 * NF, NF, 8><<<B * N / 8, NF, 0, stream>>>(
            hbuf, nW1 + (size_t)l * 2 * NF * NF, nS1 + l * NF, nB1 + l * NF, nf_next_buf[l]);
        nf_cur = nf_next_buf[l];

        // ---- edge update: pairwise MLP via MFMA ----
        k_pair_mlp_mfma<<<NPAIR / PT, 512, 0, stream>>>(
            nf_cur,
            w0t + (size_t)l * 256 * 128, eB0 + l * 256,
            w1t + (size_t)l * 256 * 256, eB1 + l * 256,
            w2t + (size_t)l * 128 * 256, eB2 + l * 128,
            w3t + (size_t)l * 128 * 128, eB3 + l * 128,
            eWout + (size_t)l * 128, eBout + l, simbuf);

        float* ef_out = (l == L - 1) ? (float*)d_out : ef_ws;
        k_edge_update<<<B * N, 128, 0, stream>>>(ef_cur, simbuf, ef_out);
        ef_cur = ef_out;
    }
}

// Round 5
// 1244.855 us; speedup vs baseline: 1.0563x; 1.0563x over previous
//
#include <hip/hip_runtime.h>
#include <math.h>

#define ALPHA 0.3f

constexpr int B  = 32;
constexpr int N  = 100;
constexpr int NF = 128;
constexpr int L  = 3;
constexpr int NN = N * N;            // 10000
constexpr int NPAIR = B * NN;        // 320000
constexpr int PT = 32;               // pairs per block in the fused MFMA MLP

typedef __attribute__((ext_vector_type(8))) short short8;
typedef __attribute__((ext_vector_type(4))) float f32x4;

__device__ __forceinline__ unsigned short f2bf(float x) {
    union { float f; unsigned u; } v; v.f = x;
    unsigned r = v.u + 0x7FFF + ((v.u >> 16) & 1);  // RNE
    return (unsigned short)(r >> 16);
}
__device__ __forceinline__ float bf2f(unsigned short h) {
    union { unsigned u; float f; } v; v.u = ((unsigned)h) << 16;
    return v.f;
}

// ---------------------------------------------------------------------------
// Weight prep: Wt[l][c][k] = W[l][k][c] * S[l][c]  (bf16, S folded)
// ---------------------------------------------------------------------------
__global__ void k_wprep(const float* __restrict__ W, const float* __restrict__ S,
                        unsigned short* __restrict__ Wt, int K, int C) {
    int idx = blockIdx.x * blockDim.x + threadIdx.x;
    int per = K * C;
    if (idx >= L * per) return;
    int l = idx / per, r = idx - l * per;
    int c = r / K, k = r - c * K;
    float v = W[(size_t)l * per + (size_t)k * C + c] * S[l * C + c];
    Wt[idx] = f2bf(v);
}

// ---------------------------------------------------------------------------
// Kernel A: per (b,m) row — L1-normalize masked edge rows, aggregate node
// features, and build x = [nf | aggr0 | aggr1]  ([B,N,3*NF])
// ---------------------------------------------------------------------------
__global__ void k_aggr_x(const float* __restrict__ nf,
                         const float* __restrict__ ef,
                         float* __restrict__ x) {
    const int b = blockIdx.x / N;
    const int m = blockIdx.x - b * N;
    const int t = threadIdx.x;  // 128 threads

    __shared__ float w0[128], w1[128];

    float e0 = 0.f, e1 = 0.f;
    if (t < N) {
        e0 = ef[((size_t)(b * 2 + 0) * N + m) * N + t];
        e1 = ef[((size_t)(b * 2 + 1) * N + m) * N + t];
        if (t == m) { e0 = 0.f; e1 = 0.f; }
    }
    w0[t] = fabsf(e0);
    w1[t] = fabsf(e1);
    __syncthreads();
    for (int s = 64; s > 0; s >>= 1) {
        if (t < s) { w0[t] += w0[t + s]; w1[t] += w1[t + s]; }
        __syncthreads();
    }
    const float s0 = w0[0];
    const float s1 = w1[0];
    __syncthreads();
    w0[t] = (s0 == 0.f) ? 0.f : e0 / s0;
    w1[t] = (s1 == 0.f) ? 0.f : e1 / s1;
    __syncthreads();

    const float* nfb = nf + (size_t)b * N * NF;
    float a0 = 0.f, a1 = 0.f;
#pragma unroll 4
    for (int n = 0; n < N; ++n) {
        const float v = nfb[(size_t)n * NF + t];
        a0 = fmaf(w0[n], v, a0);
        a1 = fmaf(w1[n], v, a1);
    }
    float* xr = x + (size_t)(b * N + m) * (3 * NF);
    xr[t]          = nfb[(size_t)m * NF + t];
    xr[NF + t]     = a0;
    xr[2 * NF + t] = a1;
}

// ---------------------------------------------------------------------------
// Kernel B: multi-row affine GEMM (f32): out = leaky((in@W)*S+Bb)
// ---------------------------------------------------------------------------
template <int K, int COUT, int R>
__global__ void k_affine_mr(const float* __restrict__ in,
                            const float* __restrict__ W,
                            const float* __restrict__ S,
                            const float* __restrict__ Bb,
                            float* __restrict__ out) {
    __shared__ float xr[R][K];
    const int r0 = blockIdx.x * R;
    const int c = threadIdx.x;  // COUT threads
    for (int idx = c; idx < R * K; idx += COUT) {
        const int rr = idx / K, kk = idx - rr * K;
        xr[rr][kk] = in[(size_t)(r0 + rr) * K + kk];
    }
    __syncthreads();
    float acc[R];
#pragma unroll
    for (int r = 0; r < R; ++r) acc[r] = 0.f;
    const float* Wc = W + c;
#pragma unroll 4
    for (int k = 0; k < K; ++k) {
        const float wv = Wc[(size_t)k * COUT];
#pragma unroll
        for (int r = 0; r < R; ++r) acc[r] = fmaf(xr[r][k], wv, acc[r]);
    }
    const float sc = S[c], bb = Bb[c];
#pragma unroll
    for (int r = 0; r < R; ++r) {
        float v = acc[r] * sc + bb;
        out[(size_t)(r0 + r) * COUT + c] = (v >= 0.f) ? v : ALPHA * v;
    }
}

// ---------------------------------------------------------------------------
// MFMA MLP layer: out[p,c] = leaky((in[p,:] @ W')[c] + Bb[c]), bf16 in/out
// in/out are swizzled LDS tiles: byte = p*(K*2) + ((col*2) ^ ((p&15)<<4))
// Wt is [COUT][K] bf16 in global (S pre-folded).
// 8 waves: wave owns cols [wave*NT*16 ...), MT M-tiles (PT pairs).
// ---------------------------------------------------------------------------
template <int K, int COUT, int NT, int MT>
__device__ __forceinline__ void layer_mfma(const unsigned short* in,
                                           unsigned short* out,
                                           const unsigned short* __restrict__ Wt,
                                           const float* __restrict__ Bb,
                                           int lane, int wave) {
    const int r16 = lane & 15, g = lane >> 4;
    f32x4 acc[MT][NT];
#pragma unroll
    for (int m = 0; m < MT; ++m)
#pragma unroll
        for (int n = 0; n < NT; ++n) acc[m][n] = (f32x4){0.f, 0.f, 0.f, 0.f};

    const int cbase = wave * NT * 16;
#pragma unroll
    for (int ks = 0; ks < K / 32; ++ks) {
        short8 av[MT];
#pragma unroll
        for (int m = 0; m < MT; ++m) {
            const int p = m * 16 + r16;
            const int byte = (ks * 64 + g * 16) ^ ((p & 15) << 4);
            av[m] = *(const short8*)((const char*)in + p * (K * 2) + byte);
        }
        short8 bv[NT];
#pragma unroll
        for (int n = 0; n < NT; ++n) {
            const int c = cbase + n * 16 + r16;
            bv[n] = *(const short8*)(Wt + (size_t)c * K + ks * 32 + g * 8);
        }
#pragma unroll
        for (int m = 0; m < MT; ++m)
#pragma unroll
            for (int n = 0; n < NT; ++n)
                acc[m][n] = __builtin_amdgcn_mfma_f32_16x16x32_bf16(
                    av[m], bv[n], acc[m][n], 0, 0, 0);
    }
#pragma unroll
    for (int n = 0; n < NT; ++n) {
        const int c = cbase + n * 16 + r16;
        const float bias = Bb[c];
#pragma unroll
        for (int m = 0; m < MT; ++m) {
#pragma unroll
            for (int r = 0; r < 4; ++r) {
                const int p = m * 16 + g * 4 + r;
                float v = acc[m][n][r] + bias;
                v = (v >= 0.f) ? v : ALPHA * v;
                const int byte = (c * 2) ^ ((p & 15) << 4);
                *(unsigned short*)((char*)out + p * (COUT * 2) + byte) = f2bf(v);
            }
        }
    }
}

// ---------------------------------------------------------------------------
// Kernel C: fused pairwise-difference MLP (bf16 MFMA) -> sim[b,i,j]
// 512 threads = 8 waves per block, 32 pairs per block; 32 KiB LDS.
// launch_bounds(512,6): ~80-reg budget (no spill) -> 3 blocks/CU, 24 waves/CU.
// (512,8) spilled: 64-reg unified budget forced 341 MB of scratch traffic.
// ---------------------------------------------------------------------------
__global__ __launch_bounds__(512, 6) void k_pair_mlp_mfma(
    const float* __restrict__ nf,
    const unsigned short* __restrict__ W0t, const float* __restrict__ Bb0,
    const unsigned short* __restrict__ W1t, const float* __restrict__ Bb1,
    const unsigned short* __restrict__ W2t, const float* __restrict__ Bb2,
    const unsigned short* __restrict__ W3t, const float* __restrict__ Bb3,
    const float* __restrict__ Wout, const float* __restrict__ boutp,
    float* __restrict__ sim) {
    __shared__ unsigned short bufA[PT * 256];  // 16 KiB
    __shared__ unsigned short bufB[PT * 256];  // 16 KiB
    const int t = threadIdx.x;
    const int lane = t & 63, wave = t >> 6;
    const int tile0 = blockIdx.x * PT;

    // Stage h0 = |nf_i - nf_j| into bufA as swizzled bf16 (row width 128ch)
    {
        const int p = t >> 4, q = t & 15;   // pair 0..31, 8-ch chunk 0..15
        const int P = tile0 + p;
        const int b = P / NN;
        int r = P - b * NN;
        const int i = r / N, j = r - i * N;
        const float4* fi = (const float4*)(nf + ((size_t)(b * N + i)) * NF + q * 8);
        const float4* fj = (const float4*)(nf + ((size_t)(b * N + j)) * NF + q * 8);
        const float4 a0 = fi[0], a1 = fi[1];
        const float4 c0 = fj[0], c1 = fj[1];
        short8 o;
        o[0] = (short)f2bf(fabsf(a0.x - c0.x));
        o[1] = (short)f2bf(fabsf(a0.y - c0.y));
        o[2] = (short)f2bf(fabsf(a0.z - c0.z));
        o[3] = (short)f2bf(fabsf(a0.w - c0.w));
        o[4] = (short)f2bf(fabsf(a1.x - c1.x));
        o[5] = (short)f2bf(fabsf(a1.y - c1.y));
        o[6] = (short)f2bf(fabsf(a1.z - c1.z));
        o[7] = (short)f2bf(fabsf(a1.w - c1.w));
        const int byte = (q * 16) ^ ((p & 15) << 4);
        *(short8*)((char*)bufA + p * 256 + byte) = o;
    }
    __syncthreads();
    layer_mfma<128, 256, 2, 2>(bufA, bufB, W0t, Bb0, lane, wave);
    __syncthreads();
    layer_mfma<256, 256, 2, 2>(bufB, bufA, W1t, Bb1, lane, wave);
    __syncthreads();
    layer_mfma<256, 128, 1, 2>(bufA, bufB, W2t, Bb2, lane, wave);
    __syncthreads();
    layer_mfma<128, 128, 1, 2>(bufB, bufA, W3t, Bb3, lane, wave);
    __syncthreads();

    // sim = sigmoid(h @ Wout + bout), h = bufA (swizzled bf16, 128 ch)
    {
        const int p = t >> 4, q = t & 15;
        const int byte = (q * 16) ^ ((p & 15) << 4);
        const short8 hv = *(const short8*)((const char*)bufA + p * 256 + byte);
        const float* wp = Wout + q * 8;
        float acc = 0.f;
#pragma unroll
        for (int d = 0; d < 8; ++d)
            acc = fmaf(bf2f((unsigned short)hv[d]), wp[d], acc);
        acc += __shfl_xor(acc, 1);
        acc += __shfl_xor(acc, 2);
        acc += __shfl_xor(acc, 4);
        acc += __shfl_xor(acc, 8);
        if (q == 0) {
            const float v = acc + boutp[0];
            sim[tile0 + p] = 1.f / (1.f + expf(-v));
        }
    }
}

// ---------------------------------------------------------------------------
// Kernel D: edge update given sim (row-local; safe in place)
// ---------------------------------------------------------------------------
__global__ void k_edge_update(const float* __restrict__ ef_in,
                              const float* __restrict__ sim,
                              float* __restrict__ ef_out) {
    const int b = blockIdx.x / N;
    const int i = blockIdx.x - b * N;
    const int t = threadIdx.x;  // 128 threads

    __shared__ float r0[128], r1[128], r2[128], r3[128];

    float e0 = 0.f, e1 = 0.f, s = 0.f;
    if (t < N) {
        e0 = ef_in[((size_t)(b * 2 + 0) * N + i) * N + t];
        e1 = ef_in[((size_t)(b * 2 + 1) * N + i) * N + t];
        if (t == i) { e0 = 0.f; e1 = 0.f; }
        s = sim[(size_t)(b * N + i) * N + t];
    }
    float f0 = e0 * s;
    float f1 = e1 * (1.f - s);
    r0[t] = e0; r1[t] = e1; r2[t] = fabsf(f0); r3[t] = fabsf(f1);
    __syncthreads();
    for (int st = 64; st > 0; st >>= 1) {
        if (t < st) {
            r0[t] += r0[t + st];
            r1[t] += r1[t + st];
            r2[t] += r2[t + st];
            r3[t] += r3[t + st];
        }
        __syncthreads();
    }
    const float m0 = r0[0], m1 = r1[0], n0 = r2[0], n1 = r3[0];
    if (t < N) {
        f0 = (n0 == 0.f) ? 0.f : (f0 / n0) * m0;
        f1 = (n1 == 0.f) ? 0.f : (f1 / n1) * m1;
        if (t == i) f0 += 1.f;
        f0 += 1e-6f;
        f1 += 1e-6f;
        const float inv = 1.f / (f0 + f1);
        ef_out[((size_t)(b * 2 + 0) * N + i) * N + t] = f0 * inv;
        ef_out[((size_t)(b * 2 + 1) * N + i) * N + t] = f1 * inv;
    }
}

// ---------------------------------------------------------------------------
extern "C" void kernel_launch(void* const* d_in, const int* in_sizes, int n_in,
                              void* d_out, int out_size, void* d_ws, size_t ws_size,
                              hipStream_t stream) {
    (void)in_sizes; (void)n_in; (void)out_size; (void)ws_size;

    const float* node_feat = (const float*)d_in[0];
    const float* edge_feat = (const float*)d_in[1];
    const float* nW0 = (const float*)d_in[2];
    const float* nS0 = (const float*)d_in[3];
    const float* nB0 = (const float*)d_in[4];
    const float* nW1 = (const float*)d_in[5];
    const float* nS1 = (const float*)d_in[6];
    const float* nB1 = (const float*)d_in[7];
    const float* eW0 = (const float*)d_in[8];
    const float* eS0 = (const float*)d_in[9];
    const float* eB0 = (const float*)d_in[10];
    const float* eW1 = (const float*)d_in[11];
    const float* eS1 = (const float*)d_in[12];
    const float* eB1 = (const float*)d_in[13];
    const float* eW2 = (const float*)d_in[14];
    const float* eS2 = (const float*)d_in[15];
    const float* eB2 = (const float*)d_in[16];
    const float* eW3 = (const float*)d_in[17];
    const float* eS3 = (const float*)d_in[18];
    const float* eB3 = (const float*)d_in[19];
    const float* eWout = (const float*)d_in[20];
    const float* eBout = (const float*)d_in[21];

    float* ws     = (float*)d_ws;
    float* nf_a   = ws;                               // B*N*NF
    float* nf_b   = nf_a + (size_t)B * N * NF;        // B*N*NF
    float* xbuf   = nf_b + (size_t)B * N * NF;        // B*N*3*NF
    float* hbuf   = xbuf + (size_t)B * N * 3 * NF;    // B*N*2*NF
    float* ef_ws  = hbuf + (size_t)B * N * 2 * NF;    // B*2*N*N
    float* simbuf = ef_ws + (size_t)B * 2 * N * N;    // B*N*N
    unsigned short* w0t = (unsigned short*)(simbuf + (size_t)B * N * N);
    unsigned short* w1t = w0t + (size_t)L * 256 * 128;   // [L][256][128]
    unsigned short* w2t = w1t + (size_t)L * 256 * 256;   // [L][256][256]
    unsigned short* w3t = w2t + (size_t)L * 128 * 256;   // [L][128][256]
    // w3t: [L][128][128]; total ws ~16.2 MB

    // --- weight prep (bf16, transposed, S folded) ---
    k_wprep<<<(L * 128 * 256 + 255) / 256, 256, 0, stream>>>(eW0, eS0, w0t, 128, 256);
    k_wprep<<<(L * 256 * 256 + 255) / 256, 256, 0, stream>>>(eW1, eS1, w1t, 256, 256);
    k_wprep<<<(L * 256 * 128 + 255) / 256, 256, 0, stream>>>(eW2, eS2, w2t, 256, 128);
    k_wprep<<<(L * 128 * 128 + 255) / 256, 256, 0, stream>>>(eW3, eS3, w3t, 128, 128);

    const float* nf_cur = node_feat;
    const float* ef_cur = edge_feat;
    float* nf_next_buf[3] = {nf_a, nf_b, nf_a};

    for (int l = 0; l < L; ++l) {
        // ---- node update (f32) ----
        k_aggr_x<<<B * N, 128, 0, stream>>>(nf_cur, ef_cur, xbuf);
        k_affine_mr<3 * NF, 2 * NF, 8><<<B * N / 8, 2 * NF, 0, stream>>>(
            xbuf, nW0 + (size_t)l * 3 * NF * 2 * NF, nS0 + l * 2 * NF, nB0 + l * 2 * NF, hbuf);
        k_affine_mr<2 * NF, NF, 8><<<B * N / 8, NF, 0, stream>>>(
            hbuf, nW1 + (size_t)l * 2 * NF * NF, nS1 + l * NF, nB1 + l * NF, nf_next_buf[l]);
        nf_cur = nf_next_buf[l];

        // ---- edge update: pairwise MLP via MFMA ----
        k_pair_mlp_mfma<<<NPAIR / PT, 512, 0, stream>>>(
            nf_cur,
            w0t + (size_t)l * 256 * 128, eB0 + l * 256,
            w1t + (size_t)l * 256 * 256, eB1 + l * 256,
            w2t + (size_t)l * 128 * 256, eB2 + l * 128,
            w3t + (size_t)l * 128 * 128, eB3 + l * 128,
            eWout + (size_t)l * 128, eBout + l, simbuf);

        float* ef_out = (l == L - 1) ? (float*)d_out : ef_ws;
        k_edge_update<<<B * N, 128, 0, stream>>>(ef_cur, simbuf, ef_out);
        ef_cur = ef_out;
    }
}

// Round 6
// 567.155 us; speedup vs baseline: 2.3185x; 2.1949x over previous
//
#include <hip/hip_runtime.h>
#include <math.h>

#define ALPHA 0.3f

constexpr int B  = 32;
constexpr int N  = 100;
constexpr int NF = 128;
constexpr int L  = 3;
constexpr int NN = N * N;            // 10000
constexpr int NPAIR = B * NN;        // 320000
constexpr int PT = 80;               // pairs per block in the fused MFMA MLP

typedef __attribute__((ext_vector_type(8))) short short8;
typedef __attribute__((ext_vector_type(4))) float f32x4;

__device__ __forceinline__ unsigned short f2bf(float x) {
    union { float f; unsigned u; } v; v.f = x;
    unsigned r = v.u + 0x7FFF + ((v.u >> 16) & 1);  // RNE
    return (unsigned short)(r >> 16);
}
__device__ __forceinline__ float bf2f(unsigned short h) {
    union { unsigned u; float f; } v; v.u = ((unsigned)h) << 16;
    return v.f;
}

// ---------------------------------------------------------------------------
// Weight prep, MFMA-fragment order:
// Wp[((l*CT+ct)*KS+ks)*64 + lane][8] = W[l][ks*32+(lane>>4)*8+j][ct*16+(lane&15)] * S
// One 16B/lane contiguous 1KiB read per B-fragment in the main kernel.
// ---------------------------------------------------------------------------
__global__ void k_wprep_frag(const float* __restrict__ W, const float* __restrict__ S,
                             unsigned short* __restrict__ Wp, int K, int C) {
    const int idx = blockIdx.x * blockDim.x + threadIdx.x;
    const int per = K * C;
    if (idx >= L * per) return;
    const int l = idx / per, r = idx - l * per;
    const int KS = K / 32;
    const int j    = r & 7;
    const int lane = (r >> 3) & 63;
    const int t2   = r >> 9;            // ct*KS + ks
    const int ks = t2 % KS, ct = t2 / KS;
    const int c = ct * 16 + (lane & 15);
    const int k = ks * 32 + (lane >> 4) * 8 + j;
    float v = W[(size_t)l * per + (size_t)k * C + c] * S[l * C + c];
    Wp[idx] = f2bf(v);
}

// ---------------------------------------------------------------------------
// Kernel A: per (b,m) row — L1-normalize masked edge rows, aggregate node
// features, and build x = [nf | aggr0 | aggr1]  ([B,N,3*NF])
// ---------------------------------------------------------------------------
__global__ void k_aggr_x(const float* __restrict__ nf,
                         const float* __restrict__ ef,
                         float* __restrict__ x) {
    const int b = blockIdx.x / N;
    const int m = blockIdx.x - b * N;
    const int t = threadIdx.x;  // 128 threads

    __shared__ float w0[128], w1[128];

    float e0 = 0.f, e1 = 0.f;
    if (t < N) {
        e0 = ef[((size_t)(b * 2 + 0) * N + m) * N + t];
        e1 = ef[((size_t)(b * 2 + 1) * N + m) * N + t];
        if (t == m) { e0 = 0.f; e1 = 0.f; }
    }
    w0[t] = fabsf(e0);
    w1[t] = fabsf(e1);
    __syncthreads();
    for (int s = 64; s > 0; s >>= 1) {
        if (t < s) { w0[t] += w0[t + s]; w1[t] += w1[t + s]; }
        __syncthreads();
    }
    const float s0 = w0[0];
    const float s1 = w1[0];
    __syncthreads();
    w0[t] = (s0 == 0.f) ? 0.f : e0 / s0;
    w1[t] = (s1 == 0.f) ? 0.f : e1 / s1;
    __syncthreads();

    const float* nfb = nf + (size_t)b * N * NF;
    float a0 = 0.f, a1 = 0.f;
#pragma unroll 4
    for (int n = 0; n < N; ++n) {
        const float v = nfb[(size_t)n * NF + t];
        a0 = fmaf(w0[n], v, a0);
        a1 = fmaf(w1[n], v, a1);
    }
    float* xr = x + (size_t)(b * N + m) * (3 * NF);
    xr[t]          = nfb[(size_t)m * NF + t];
    xr[NF + t]     = a0;
    xr[2 * NF + t] = a1;
}

// ---------------------------------------------------------------------------
// Kernel B: multi-row affine GEMM (f32): out = leaky((in@W)*S+Bb)
// ---------------------------------------------------------------------------
template <int K, int COUT, int R>
__global__ void k_affine_mr(const float* __restrict__ in,
                            const float* __restrict__ W,
                            const float* __restrict__ S,
                            const float* __restrict__ Bb,
                            float* __restrict__ out) {
    __shared__ float xr[R][K];
    const int r0 = blockIdx.x * R;
    const int c = threadIdx.x;  // COUT threads
    for (int idx = c; idx < R * K; idx += COUT) {
        const int rr = idx / K, kk = idx - rr * K;
        xr[rr][kk] = in[(size_t)(r0 + rr) * K + kk];
    }
    __syncthreads();
    float acc[R];
#pragma unroll
    for (int r = 0; r < R; ++r) acc[r] = 0.f;
    const float* Wc = W + c;
#pragma unroll 4
    for (int k = 0; k < K; ++k) {
        const float wv = Wc[(size_t)k * COUT];
#pragma unroll
        for (int r = 0; r < R; ++r) acc[r] = fmaf(xr[r][k], wv, acc[r]);
    }
    const float sc = S[c], bb = Bb[c];
#pragma unroll
    for (int r = 0; r < R; ++r) {
        float v = acc[r] * sc + bb;
        out[(size_t)(r0 + r) * COUT + c] = (v >= 0.f) ? v : ALPHA * v;
    }
}

// ---------------------------------------------------------------------------
// Prefetch a layer's ks=0 B-fragments (issued before the preceding barrier;
// the barrier's vmcnt drain makes them resident when the layer starts).
// ---------------------------------------------------------------------------
template <int K, int NT>
__device__ __forceinline__ void load_bv0(const unsigned short* __restrict__ Wf,
                                         int lane, int wave, short8* bv) {
    constexpr int KS = K / 32;
#pragma unroll
    for (int n = 0; n < NT; ++n)
        bv[n] = *(const short8*)(Wf + (((size_t)(wave * NT + n) * KS) * 64 + lane) * 8);
}

// ---------------------------------------------------------------------------
// MFMA MLP layer: out[p,c] = leaky((in[p,:] @ W')[c] + Bb[c]), bf16 in/out
// in/out are swizzled LDS tiles: byte = p*(K*2) + ((col*2) ^ ((p&15)<<4))
// Wf is fragment-ordered bf16 weights (S pre-folded), 1KiB coalesced/fragment.
// 8 waves: wave owns cols [wave*NT*16 ...), MT M-tiles (PT=MT*16 pairs).
// ---------------------------------------------------------------------------
template <int K, int COUT, int NT, int MT>
__device__ __forceinline__ void layer_mfma(const unsigned short* in,
                                           unsigned short* out,
                                           const unsigned short* __restrict__ Wf,
                                           const float* __restrict__ Bb,
                                           int lane, int wave, const short8* bv0) {
    constexpr int KS = K / 32;
    const int r16 = lane & 15, g = lane >> 4;
    f32x4 acc[MT][NT];
#pragma unroll
    for (int m = 0; m < MT; ++m)
#pragma unroll
        for (int n = 0; n < NT; ++n) acc[m][n] = (f32x4){0.f, 0.f, 0.f, 0.f};

#pragma unroll
    for (int ks = 0; ks < KS; ++ks) {
        short8 av[MT];
        const int abyte = (ks * 64 + g * 16) ^ (r16 << 4);
#pragma unroll
        for (int m = 0; m < MT; ++m) {
            const int p = m * 16 + r16;
            av[m] = *(const short8*)((const char*)in + p * (K * 2) + abyte);
        }
        short8 bv[NT];
#pragma unroll
        for (int n = 0; n < NT; ++n) {
            if (ks == 0) bv[n] = bv0[n];
            else bv[n] = *(const short8*)(Wf + (((size_t)(wave * NT + n) * KS + ks) * 64 + lane) * 8);
        }
#pragma unroll
        for (int m = 0; m < MT; ++m)
#pragma unroll
            for (int n = 0; n < NT; ++n)
                acc[m][n] = __builtin_amdgcn_mfma_f32_16x16x32_bf16(
                    av[m], bv[n], acc[m][n], 0, 0, 0);
    }
#pragma unroll
    for (int n = 0; n < NT; ++n) {
        const int c = wave * NT * 16 + n * 16 + r16;
        const float bias = Bb[c];
#pragma unroll
        for (int m = 0; m < MT; ++m) {
#pragma unroll
            for (int r = 0; r < 4; ++r) {
                const int p = m * 16 + g * 4 + r;
                float v = acc[m][n][r] + bias;
                v = (v >= 0.f) ? v : ALPHA * v;
                const int byte = (c * 2) ^ ((p & 15) << 4);
                *(unsigned short*)((char*)out + p * (COUT * 2) + byte) = f2bf(v);
            }
        }
    }
}

// ---------------------------------------------------------------------------
// Kernel C: fused pairwise-difference MLP (bf16 MFMA) -> sim[b,i,j]
// 512 threads = 8 waves, 80 pairs per block; 80 KiB LDS -> 2 blocks/CU.
// launch_bounds(512,4): 128-reg budget, demand ~96-110, no spill.
// (512,8) spilled catastrophically (R3); PT=32 starved barrier intervals (R4).
// ---------------------------------------------------------------------------
__global__ __launch_bounds__(512, 4) void k_pair_mlp_mfma(
    const float* __restrict__ nf,
    const unsigned short* __restrict__ W0f, const float* __restrict__ Bb0,
    const unsigned short* __restrict__ W1f, const float* __restrict__ Bb1,
    const unsigned short* __restrict__ W2f, const float* __restrict__ Bb2,
    const unsigned short* __restrict__ W3f, const float* __restrict__ Bb3,
    const float* __restrict__ Wout, const float* __restrict__ boutp,
    float* __restrict__ sim) {
    __shared__ unsigned short bufA[PT * 256];  // 40 KiB
    __shared__ unsigned short bufB[PT * 256];  // 40 KiB
    const int t = threadIdx.x;
    const int lane = t & 63, wave = t >> 6;
    const int tile0 = blockIdx.x * PT;

    // Stage h0 = |nf_i - nf_j| into bufA as swizzled bf16 (row width 128ch)
    {
        const int p0 = t >> 4, q = t & 15;   // 8-ch chunk per thread
        for (int p = p0; p < PT; p += 32) {
            const int P = tile0 + p;
            const int b = P / NN;
            int r = P - b * NN;
            const int i = r / N, j = r - i * N;
            const float4* fi = (const float4*)(nf + ((size_t)(b * N + i)) * NF + q * 8);
            const float4* fj = (const float4*)(nf + ((size_t)(b * N + j)) * NF + q * 8);
            const float4 a0 = fi[0], a1 = fi[1];
            const float4 c0 = fj[0], c1 = fj[1];
            short8 o;
            o[0] = (short)f2bf(fabsf(a0.x - c0.x));
            o[1] = (short)f2bf(fabsf(a0.y - c0.y));
            o[2] = (short)f2bf(fabsf(a0.z - c0.z));
            o[3] = (short)f2bf(fabsf(a0.w - c0.w));
            o[4] = (short)f2bf(fabsf(a1.x - c1.x));
            o[5] = (short)f2bf(fabsf(a1.y - c1.y));
            o[6] = (short)f2bf(fabsf(a1.z - c1.z));
            o[7] = (short)f2bf(fabsf(a1.w - c1.w));
            const int byte = (q * 16) ^ ((p & 15) << 4);
            *(short8*)((char*)bufA + p * 256 + byte) = o;
        }
    }
    short8 bvp[2];
    load_bv0<128, 2>(W0f, lane, wave, bvp);
    __syncthreads();
    layer_mfma<128, 256, 2, 5>(bufA, bufB, W0f, Bb0, lane, wave, bvp);
    load_bv0<256, 2>(W1f, lane, wave, bvp);
    __syncthreads();
    layer_mfma<256, 256, 2, 5>(bufB, bufA, W1f, Bb1, lane, wave, bvp);
    load_bv0<256, 1>(W2f, lane, wave, bvp);
    __syncthreads();
    layer_mfma<256, 128, 1, 5>(bufA, bufB, W2f, Bb2, lane, wave, bvp);
    load_bv0<128, 1>(W3f, lane, wave, bvp);
    __syncthreads();
    layer_mfma<128, 128, 1, 5>(bufB, bufA, W3f, Bb3, lane, wave, bvp);
    __syncthreads();

    // sim = sigmoid(h @ Wout + bout), h = bufA (swizzled bf16, 128 ch)
    {
        const int p0 = t >> 3, q = t & 7;   // 16-ch per thread
        for (int pp = p0; pp < PT; pp += 64) {
            float acc = 0.f;
#pragma unroll
            for (int u = 0; u < 2; ++u) {
                const int byte = (q * 32 + u * 16) ^ ((pp & 15) << 4);
                const short8 hv = *(const short8*)((const char*)bufA + pp * 256 + byte);
                const float* wp = Wout + q * 16 + u * 8;
#pragma unroll
                for (int d = 0; d < 8; ++d)
                    acc = fmaf(bf2f((unsigned short)hv[d]), wp[d], acc);
            }
            acc += __shfl_xor(acc, 1);
            acc += __shfl_xor(acc, 2);
            acc += __shfl_xor(acc, 4);
            if (q == 0) {
                const float v = acc + boutp[0];
                sim[tile0 + pp] = 1.f / (1.f + expf(-v));
            }
        }
    }
}

// ---------------------------------------------------------------------------
// Kernel D: edge update given sim (row-local; safe in place)
// ---------------------------------------------------------------------------
__global__ void k_edge_update(const float* __restrict__ ef_in,
                              const float* __restrict__ sim,
                              float* __restrict__ ef_out) {
    const int b = blockIdx.x / N;
    const int i = blockIdx.x - b * N;
    const int t = threadIdx.x;  // 128 threads

    __shared__ float r0[128], r1[128], r2[128], r3[128];

    float e0 = 0.f, e1 = 0.f, s = 0.f;
    if (t < N) {
        e0 = ef_in[((size_t)(b * 2 + 0) * N + i) * N + t];
        e1 = ef_in[((size_t)(b * 2 + 1) * N + i) * N + t];
        if (t == i) { e0 = 0.f; e1 = 0.f; }
        s = sim[(size_t)(b * N + i) * N + t];
    }
    float f0 = e0 * s;
    float f1 = e1 * (1.f - s);
    r0[t] = e0; r1[t] = e1; r2[t] = fabsf(f0); r3[t] = fabsf(f1);
    __syncthreads();
    for (int st = 64; st > 0; st >>= 1) {
        if (t < st) {
            r0[t] += r0[t + st];
            r1[t] += r1[t + st];
            r2[t] += r2[t + st];
            r3[t] += r3[t + st];
        }
        __syncthreads();
    }
    const float m0 = r0[0], m1 = r1[0], n0 = r2[0], n1 = r3[0];
    if (t < N) {
        f0 = (n0 == 0.f) ? 0.f : (f0 / n0) * m0;
        f1 = (n1 == 0.f) ? 0.f : (f1 / n1) * m1;
        if (t == i) f0 += 1.f;
        f0 += 1e-6f;
        f1 += 1e-6f;
        const float inv = 1.f / (f0 + f1);
        ef_out[((size_t)(b * 2 + 0) * N + i) * N + t] = f0 * inv;
        ef_out[((size_t)(b * 2 + 1) * N + i) * N + t] = f1 * inv;
    }
}

// ---------------------------------------------------------------------------
extern "C" void kernel_launch(void* const* d_in, const int* in_sizes, int n_in,
                              void* d_out, int out_size, void* d_ws, size_t ws_size,
                              hipStream_t stream) {
    (void)in_sizes; (void)n_in; (void)out_size; (void)ws_size;

    const float* node_feat = (const float*)d_in[0];
    const float* edge_feat = (const float*)d_in[1];
    const float* nW0 = (const float*)d_in[2];
    const float* nS0 = (const float*)d_in[3];
    const float* nB0 = (const float*)d_in[4];
    const float* nW1 = (const float*)d_in[5];
    const float* nS1 = (const float*)d_in[6];
    const float* nB1 = (const float*)d_in[7];
    const float* eW0 = (const float*)d_in[8];
    const float* eS0 = (const float*)d_in[9];
    const float* eB0 = (const float*)d_in[10];
    const float* eW1 = (const float*)d_in[11];
    const float* eS1 = (const float*)d_in[12];
    const float* eB1 = (const float*)d_in[13];
    const float* eW2 = (const float*)d_in[14];
    const float* eS2 = (const float*)d_in[15];
    const float* eB2 = (const float*)d_in[16];
    const float* eW3 = (const float*)d_in[17];
    const float* eS3 = (const float*)d_in[18];
    const float* eB3 = (const float*)d_in[19];
    const float* eWout = (const float*)d_in[20];
    const float* eBout = (const float*)d_in[21];

    float* ws     = (float*)d_ws;
    float* nf_a   = ws;                               // B*N*NF
    float* nf_b   = nf_a + (size_t)B * N * NF;        // B*N*NF
    float* xbuf   = nf_b + (size_t)B * N * NF;        // B*N*3*NF
    float* hbuf   = xbuf + (size_t)B * N * 3 * NF;    // B*N*2*NF
    float* ef_ws  = hbuf + (size_t)B * N * 2 * NF;    // B*2*N*N
    float* simbuf = ef_ws + (size_t)B * 2 * N * N;    // B*N*N
    unsigned short* w0t = (unsigned short*)(simbuf + (size_t)B * N * N);
    unsigned short* w1t = w0t + (size_t)L * 256 * 128;   // fragment-ordered
    unsigned short* w2t = w1t + (size_t)L * 256 * 256;
    unsigned short* w3t = w2t + (size_t)L * 128 * 256;
    // total ws ~16.2 MB

    // --- weight prep (bf16, fragment-ordered, S folded) ---
    k_wprep_frag<<<(L * 128 * 256 + 255) / 256, 256, 0, stream>>>(eW0, eS0, w0t, 128, 256);
    k_wprep_frag<<<(L * 256 * 256 + 255) / 256, 256, 0, stream>>>(eW1, eS1, w1t, 256, 256);
    k_wprep_frag<<<(L * 256 * 128 + 255) / 256, 256, 0, stream>>>(eW2, eS2, w2t, 256, 128);
    k_wprep_frag<<<(L * 128 * 128 + 255) / 256, 256, 0, stream>>>(eW3, eS3, w3t, 128, 128);

    const float* nf_cur = node_feat;
    const float* ef_cur = edge_feat;
    float* nf_next_buf[3] = {nf_a, nf_b, nf_a};

    for (int l = 0; l < L; ++l) {
        // ---- node update (f32) ----
        k_aggr_x<<<B * N, 128, 0, stream>>>(nf_cur, ef_cur, xbuf);
        k_affine_mr<3 * NF, 2 * NF, 8><<<B * N / 8, 2 * NF, 0, stream>>>(
            xbuf, nW0 + (size_t)l * 3 * NF * 2 * NF, nS0 + l * 2 * NF, nB0 + l * 2 * NF, hbuf);
        k_affine_mr<2 * NF, NF, 8><<<B * N / 8, NF, 0, stream>>>(
            hbuf, nW1 + (size_t)l * 2 * NF * NF, nS1 + l * NF, nB1 + l * NF, nf_next_buf[l]);
        nf_cur = nf_next_buf[l];

        // ---- edge update: pairwise MLP via MFMA ----
        k_pair_mlp_mfma<<<NPAIR / PT, 512, 0, stream>>>(
            nf_cur,
            w0t + (size_t)l * 256 * 128, eB0 + l * 256,
            w1t + (size_t)l * 256 * 256, eB1 + l * 256,
            w2t + (size_t)l * 128 * 256, eB2 + l * 128,
            w3t + (size_t)l * 128 * 128, eB3 + l * 128,
            eWout + (size_t)l * 128, eBout + l, simbuf);

        float* ef_out = (l == L - 1) ? (float*)d_out : ef_ws;
        k_edge_update<<<B * N, 128, 0, stream>>>(ef_cur, simbuf, ef_out);
        ef_cur = ef_out;
    }
}

// Round 7
// 512.050 us; speedup vs baseline: 2.5680x; 1.1076x over previous
//
#include <hip/hip_runtime.h>
#include <math.h>

#define ALPHA 0.3f

constexpr int B  = 32;
constexpr int N  = 100;
constexpr int NF = 128;
constexpr int L  = 3;
constexpr int NN = N * N;            // 10000
constexpr int NPAIR = B * NN;        // 320000
constexpr int PT = 80;               // pairs per block in the fused MFMA MLP

typedef __attribute__((ext_vector_type(8))) short short8;
typedef __attribute__((ext_vector_type(4))) float f32x4;

__device__ __forceinline__ unsigned short f2bf(float x) {
    union { float f; unsigned u; } v; v.f = x;
    unsigned r = v.u + 0x7FFF + ((v.u >> 16) & 1);  // RNE
    return (unsigned short)(r >> 16);
}
__device__ __forceinline__ float bf2f(unsigned short h) {
    union { unsigned u; float f; } v; v.u = ((unsigned)h) << 16;
    return v.f;
}
// packed f32x2 -> bf16x2 (RNE, same rounding as f2bf)
__device__ __forceinline__ unsigned cvt_pk(float lo, float hi) {
    unsigned r;
    asm("v_cvt_pk_bf16_f32 %0, %1, %2" : "=v"(r) : "v"(lo), "v"(hi));
    return r;
}

// ---------------------------------------------------------------------------
// Weight prep, MFMA-fragment order:
// Wp[((l*CT+ct)*KS+ks)*64 + lane][8] = W[l][ks*32+(lane>>4)*8+j][ct*16+(lane&15)] * S
// ---------------------------------------------------------------------------
__global__ void k_wprep_frag(const float* __restrict__ W, const float* __restrict__ S,
                             unsigned short* __restrict__ Wp, int K, int C) {
    const int idx = blockIdx.x * blockDim.x + threadIdx.x;
    const int per = K * C;
    if (idx >= L * per) return;
    const int l = idx / per, r = idx - l * per;
    const int KS = K / 32;
    const int j    = r & 7;
    const int lane = (r >> 3) & 63;
    const int t2   = r >> 9;            // ct*KS + ks
    const int ks = t2 % KS, ct = t2 / KS;
    const int c = ct * 16 + (lane & 15);
    const int k = ks * 32 + (lane >> 4) * 8 + j;
    float v = W[(size_t)l * per + (size_t)k * C + c] * S[l * C + c];
    Wp[idx] = f2bf(v);
}

// ---------------------------------------------------------------------------
// Kernel A: per (b,m) row — L1-normalize masked edge rows, aggregate node
// features, and build x = [nf | aggr0 | aggr1]  ([B,N,3*NF])
// ---------------------------------------------------------------------------
__global__ void k_aggr_x(const float* __restrict__ nf,
                         const float* __restrict__ ef,
                         float* __restrict__ x) {
    const int b = blockIdx.x / N;
    const int m = blockIdx.x - b * N;
    const int t = threadIdx.x;  // 128 threads

    __shared__ float w0[128], w1[128];

    float e0 = 0.f, e1 = 0.f;
    if (t < N) {
        e0 = ef[((size_t)(b * 2 + 0) * N + m) * N + t];
        e1 = ef[((size_t)(b * 2 + 1) * N + m) * N + t];
        if (t == m) { e0 = 0.f; e1 = 0.f; }
    }
    w0[t] = fabsf(e0);
    w1[t] = fabsf(e1);
    __syncthreads();
    for (int s = 64; s > 0; s >>= 1) {
        if (t < s) { w0[t] += w0[t + s]; w1[t] += w1[t + s]; }
        __syncthreads();
    }
    const float s0 = w0[0];
    const float s1 = w1[0];
    __syncthreads();
    w0[t] = (s0 == 0.f) ? 0.f : e0 / s0;
    w1[t] = (s1 == 0.f) ? 0.f : e1 / s1;
    __syncthreads();

    const float* nfb = nf + (size_t)b * N * NF;
    float a0 = 0.f, a1 = 0.f;
#pragma unroll 4
    for (int n = 0; n < N; ++n) {
        const float v = nfb[(size_t)n * NF + t];
        a0 = fmaf(w0[n], v, a0);
        a1 = fmaf(w1[n], v, a1);
    }
    float* xr = x + (size_t)(b * N + m) * (3 * NF);
    xr[t]          = nfb[(size_t)m * NF + t];
    xr[NF + t]     = a0;
    xr[2 * NF + t] = a1;
}

// ---------------------------------------------------------------------------
// Kernel B: multi-row affine GEMM (f32): out = leaky((in@W)*S+Bb)
// ---------------------------------------------------------------------------
template <int K, int COUT, int R>
__global__ void k_affine_mr(const float* __restrict__ in,
                            const float* __restrict__ W,
                            const float* __restrict__ S,
                            const float* __restrict__ Bb,
                            float* __restrict__ out) {
    __shared__ float xr[R][K];
    const int r0 = blockIdx.x * R;
    const int c = threadIdx.x;  // COUT threads
    for (int idx = c; idx < R * K; idx += COUT) {
        const int rr = idx / K, kk = idx - rr * K;
        xr[rr][kk] = in[(size_t)(r0 + rr) * K + kk];
    }
    __syncthreads();
    float acc[R];
#pragma unroll
    for (int r = 0; r < R; ++r) acc[r] = 0.f;
    const float* Wc = W + c;
#pragma unroll 4
    for (int k = 0; k < K; ++k) {
        const float wv = Wc[(size_t)k * COUT];
#pragma unroll
        for (int r = 0; r < R; ++r) acc[r] = fmaf(xr[r][k], wv, acc[r]);
    }
    const float sc = S[c], bb = Bb[c];
#pragma unroll
    for (int r = 0; r < R; ++r) {
        float v = acc[r] * sc + bb;
        out[(size_t)(r0 + r) * COUT + c] = (v >= 0.f) ? v : ALPHA * v;
    }
}

// ---------------------------------------------------------------------------
// Prefetch a layer's ks=0 B-fragments (issued before the preceding barrier).
// ---------------------------------------------------------------------------
template <int K, int NT>
__device__ __forceinline__ void load_bv0(const unsigned short* __restrict__ Wf,
                                         int lane, int wave, short8* bv) {
    constexpr int KS = K / 32;
#pragma unroll
    for (int n = 0; n < NT; ++n)
        bv[n] = *(const short8*)(Wf + (((size_t)(wave * NT + n) * KS) * 64 + lane) * 8);
}

// ---------------------------------------------------------------------------
// MFMA MLP layer (SWAPPED operands): D = W' x h^T, so lane holds 4 consecutive
// output CHANNELS of one pair -> packed 8-byte LDS writes.
// in/out swizzled LDS tiles: channel c of pair p at byte p*(W*2) + ((2c)^((p&15)<<4))
// ---------------------------------------------------------------------------
template <int K, int COUT, int NT, int MT>
__device__ __forceinline__ void layer_mfma(const unsigned short* in,
                                           unsigned short* out,
                                           const unsigned short* __restrict__ Wf,
                                           const float* __restrict__ Bb,
                                           int lane, int wave, const short8* bv0) {
    constexpr int KS = K / 32;
    const int r16 = lane & 15, g = lane >> 4;
    f32x4 acc[MT][NT];
#pragma unroll
    for (int m = 0; m < MT; ++m)
#pragma unroll
        for (int n = 0; n < NT; ++n) acc[m][n] = (f32x4){0.f, 0.f, 0.f, 0.f};

#pragma unroll
    for (int ks = 0; ks < KS; ++ks) {
        short8 av[MT];
        const int abyte = (ks * 64 + g * 16) ^ (r16 << 4);
#pragma unroll
        for (int m = 0; m < MT; ++m) {
            const int p = m * 16 + r16;
            av[m] = *(const short8*)((const char*)in + p * (K * 2) + abyte);
        }
        short8 bv[NT];
#pragma unroll
        for (int n = 0; n < NT; ++n) {
            if (ks == 0) bv[n] = bv0[n];
            else bv[n] = *(const short8*)(Wf + (((size_t)(wave * NT + n) * KS + ks) * 64 + lane) * 8);
        }
        // swapped: weights as A, activations as B -> D[c][p]
#pragma unroll
        for (int m = 0; m < MT; ++m)
#pragma unroll
            for (int n = 0; n < NT; ++n)
                acc[m][n] = __builtin_amdgcn_mfma_f32_16x16x32_bf16(
                    bv[n], av[m], acc[m][n], 0, 0, 0);
    }
    // epilogue: lane holds channels c0..c0+3 (regs) of pair p = m*16 + r16
#pragma unroll
    for (int n = 0; n < NT; ++n) {
        const int c0 = wave * NT * 16 + n * 16 + g * 4;
        const float4 b4 = *(const float4*)(Bb + c0);
#pragma unroll
        for (int m = 0; m < MT; ++m) {
            const int p = m * 16 + r16;
            float v0 = acc[m][n][0] + b4.x; v0 = fmaxf(v0, ALPHA * v0);
            float v1 = acc[m][n][1] + b4.y; v1 = fmaxf(v1, ALPHA * v1);
            float v2 = acc[m][n][2] + b4.z; v2 = fmaxf(v2, ALPHA * v2);
            float v3 = acc[m][n][3] + b4.w; v3 = fmaxf(v3, ALPHA * v3);
            uint2 w;
            w.x = cvt_pk(v0, v1);
            w.y = cvt_pk(v2, v3);
            const int byte = (c0 * 2) ^ (r16 << 4);
            *(uint2*)((char*)out + p * (COUT * 2) + byte) = w;
        }
    }
}

// ---------------------------------------------------------------------------
// Kernel C: fused pairwise-difference MLP (bf16 MFMA) -> sim[b,i,j]
// 512 threads = 8 waves, 80 pairs per block; 80 KiB LDS -> 2 blocks/CU.
// ---------------------------------------------------------------------------
__global__ __launch_bounds__(512, 4) void k_pair_mlp_mfma(
    const float* __restrict__ nf,
    const unsigned short* __restrict__ W0f, const float* __restrict__ Bb0,
    const unsigned short* __restrict__ W1f, const float* __restrict__ Bb1,
    const unsigned short* __restrict__ W2f, const float* __restrict__ Bb2,
    const unsigned short* __restrict__ W3f, const float* __restrict__ Bb3,
    const float* __restrict__ Wout, const float* __restrict__ boutp,
    float* __restrict__ sim) {
    __shared__ unsigned short bufA[PT * 256];  // 40 KiB
    __shared__ unsigned short bufB[PT * 256];  // 40 KiB
    const int t = threadIdx.x;
    const int lane = t & 63, wave = t >> 6;
    const int tile0 = blockIdx.x * PT;

    // Stage h0 = |nf_i - nf_j| into bufA as swizzled bf16 (row width 128ch)
    {
        const int p0 = t >> 4, q = t & 15;   // 8-ch chunk per thread
        for (int p = p0; p < PT; p += 32) {
            const int P = tile0 + p;
            const int b = P / NN;
            int r = P - b * NN;
            const int i = r / N, j = r - i * N;
            const float4* fi = (const float4*)(nf + ((size_t)(b * N + i)) * NF + q * 8);
            const float4* fj = (const float4*)(nf + ((size_t)(b * N + j)) * NF + q * 8);
            const float4 a0 = fi[0], a1 = fi[1];
            const float4 c0 = fj[0], c1 = fj[1];
            uint4 o;
            o.x = cvt_pk(fabsf(a0.x - c0.x), fabsf(a0.y - c0.y));
            o.y = cvt_pk(fabsf(a0.z - c0.z), fabsf(a0.w - c0.w));
            o.z = cvt_pk(fabsf(a1.x - c1.x), fabsf(a1.y - c1.y));
            o.w = cvt_pk(fabsf(a1.z - c1.z), fabsf(a1.w - c1.w));
            const int byte = (q * 16) ^ ((p & 15) << 4);
            *(uint4*)((char*)bufA + p * 256 + byte) = o;
        }
    }
    short8 bvp[2];
    load_bv0<128, 2>(W0f, lane, wave, bvp);
    __syncthreads();
    layer_mfma<128, 256, 2, 5>(bufA, bufB, W0f, Bb0, lane, wave, bvp);
    load_bv0<256, 2>(W1f, lane, wave, bvp);
    __syncthreads();
    layer_mfma<256, 256, 2, 5>(bufB, bufA, W1f, Bb1, lane, wave, bvp);
    load_bv0<256, 1>(W2f, lane, wave, bvp);
    __syncthreads();
    layer_mfma<256, 128, 1, 5>(bufA, bufB, W2f, Bb2, lane, wave, bvp);
    load_bv0<128, 1>(W3f, lane, wave, bvp);
    __syncthreads();
    layer_mfma<128, 128, 1, 5>(bufB, bufA, W3f, Bb3, lane, wave, bvp);
    __syncthreads();

    // sim = sigmoid(h @ Wout + bout), h = bufA (swizzled bf16, 128 ch)
    {
        const int p0 = t >> 3, q = t & 7;   // 16-ch per thread
        for (int pp = p0; pp < PT; pp += 64) {
            float acc = 0.f;
#pragma unroll
            for (int u = 0; u < 2; ++u) {
                const int byte = (q * 32 + u * 16) ^ ((pp & 15) << 4);
                const short8 hv = *(const short8*)((const char*)bufA + pp * 256 + byte);
                const float* wp = Wout + q * 16 + u * 8;
#pragma unroll
                for (int d = 0; d < 8; ++d)
                    acc = fmaf(bf2f((unsigned short)hv[d]), wp[d], acc);
            }
            acc += __shfl_xor(acc, 1);
            acc += __shfl_xor(acc, 2);
            acc += __shfl_xor(acc, 4);
            if (q == 0) {
                const float v = acc + boutp[0];
                sim[tile0 + pp] = 1.f / (1.f + expf(-v));
            }
        }
    }
}

// ---------------------------------------------------------------------------
// Kernel D: edge update given sim (row-local; safe in place)
// ---------------------------------------------------------------------------
__global__ void k_edge_update(const float* __restrict__ ef_in,
                              const float* __restrict__ sim,
                              float* __restrict__ ef_out) {
    const int b = blockIdx.x / N;
    const int i = blockIdx.x - b * N;
    const int t = threadIdx.x;  // 128 threads

    __shared__ float r0[128], r1[128], r2[128], r3[128];

    float e0 = 0.f, e1 = 0.f, s = 0.f;
    if (t < N) {
        e0 = ef_in[((size_t)(b * 2 + 0) * N + i) * N + t];
        e1 = ef_in[((size_t)(b * 2 + 1) * N + i) * N + t];
        if (t == i) { e0 = 0.f; e1 = 0.f; }
        s = sim[(size_t)(b * N + i) * N + t];
    }
    float f0 = e0 * s;
    float f1 = e1 * (1.f - s);
    r0[t] = e0; r1[t] = e1; r2[t] = fabsf(f0); r3[t] = fabsf(f1);
    __syncthreads();
    for (int st = 64; st > 0; st >>= 1) {
        if (t < st) {
            r0[t] += r0[t + st];
            r1[t] += r1[t + st];
            r2[t] += r2[t + st];
            r3[t] += r3[t + st];
        }
        __syncthreads();
    }
    const float m0 = r0[0], m1 = r1[0], n0 = r2[0], n1 = r3[0];
    if (t < N) {
        f0 = (n0 == 0.f) ? 0.f : (f0 / n0) * m0;
        f1 = (n1 == 0.f) ? 0.f : (f1 / n1) * m1;
        if (t == i) f0 += 1.f;
        f0 += 1e-6f;
        f1 += 1e-6f;
        const float inv = 1.f / (f0 + f1);
        ef_out[((size_t)(b * 2 + 0) * N + i) * N + t] = f0 * inv;
        ef_out[((size_t)(b * 2 + 1) * N + i) * N + t] = f1 * inv;
    }
}

// ---------------------------------------------------------------------------
extern "C" void kernel_launch(void* const* d_in, const int* in_sizes, int n_in,
                              void* d_out, int out_size, void* d_ws, size_t ws_size,
                              hipStream_t stream) {
    (void)in_sizes; (void)n_in; (void)out_size; (void)ws_size;

    const float* node_feat = (const float*)d_in[0];
    const float* edge_feat = (const float*)d_in[1];
    const float* nW0 = (const float*)d_in[2];
    const float* nS0 = (const float*)d_in[3];
    const float* nB0 = (const float*)d_in[4];
    const float* nW1 = (const float*)d_in[5];
    const float* nS1 = (const float*)d_in[6];
    const float* nB1 = (const float*)d_in[7];
    const float* eW0 = (const float*)d_in[8];
    const float* eS0 = (const float*)d_in[9];
    const float* eB0 = (const float*)d_in[10];
    const float* eW1 = (const float*)d_in[11];
    const float* eS1 = (const float*)d_in[12];
    const float* eB1 = (const float*)d_in[13];
    const float* eW2 = (const float*)d_in[14];
    const float* eS2 = (const float*)d_in[15];
    const float* eB2 = (const float*)d_in[16];
    const float* eW3 = (const float*)d_in[17];
    const float* eS3 = (const float*)d_in[18];
    const float* eB3 = (const float*)d_in[19];
    const float* eWout = (const float*)d_in[20];
    const float* eBout = (const float*)d_in[21];

    float* ws     = (float*)d_ws;
    float* nf_a   = ws;                               // B*N*NF
    float* nf_b   = nf_a + (size_t)B * N * NF;        // B*N*NF
    float* xbuf   = nf_b + (size_t)B * N * NF;        // B*N*3*NF
    float* hbuf   = xbuf + (size_t)B * N * 3 * NF;    // B*N*2*NF
    float* ef_ws  = hbuf + (size_t)B * N * 2 * NF;    // B*2*N*N
    float* simbuf = ef_ws + (size_t)B * 2 * N * N;    // B*N*N
    unsigned short* w0t = (unsigned short*)(simbuf + (size_t)B * N * N);
    unsigned short* w1t = w0t + (size_t)L * 256 * 128;   // fragment-ordered
    unsigned short* w2t = w1t + (size_t)L * 256 * 256;
    unsigned short* w3t = w2t + (size_t)L * 128 * 256;
    // total ws ~16.2 MB

    // --- weight prep (bf16, fragment-ordered, S folded) ---
    k_wprep_frag<<<(L * 128 * 256 + 255) / 256, 256, 0, stream>>>(eW0, eS0, w0t, 128, 256);
    k_wprep_frag<<<(L * 256 * 256 + 255) / 256, 256, 0, stream>>>(eW1, eS1, w1t, 256, 256);
    k_wprep_frag<<<(L * 256 * 128 + 255) / 256, 256, 0, stream>>>(eW2, eS2, w2t, 256, 128);
    k_wprep_frag<<<(L * 128 * 128 + 255) / 256, 256, 0, stream>>>(eW3, eS3, w3t, 128, 128);

    const float* nf_cur = node_feat;
    const float* ef_cur = edge_feat;
    float* nf_next_buf[3] = {nf_a, nf_b, nf_a};

    for (int l = 0; l < L; ++l) {
        // ---- node update (f32) ----
        k_aggr_x<<<B * N, 128, 0, stream>>>(nf_cur, ef_cur, xbuf);
        k_affine_mr<3 * NF, 2 * NF, 8><<<B * N / 8, 2 * NF, 0, stream>>>(
            xbuf, nW0 + (size_t)l * 3 * NF * 2 * NF, nS0 + l * 2 * NF, nB0 + l * 2 * NF, hbuf);
        k_affine_mr<2 * NF, NF, 8><<<B * N / 8, NF, 0, stream>>>(
            hbuf, nW1 + (size_t)l * 2 * NF * NF, nS1 + l * NF, nB1 + l * NF, nf_next_buf[l]);
        nf_cur = nf_next_buf[l];

        // ---- edge update: pairwise MLP via MFMA ----
        k_pair_mlp_mfma<<<NPAIR / PT, 512, 0, stream>>>(
            nf_cur,
            w0t + (size_t)l * 256 * 128, eB0 + l * 256,
            w1t + (size_t)l * 256 * 256, eB1 + l * 256,
            w2t + (size_t)l * 128 * 256, eB2 + l * 128,
            w3t + (size_t)l * 128 * 128, eB3 + l * 128,
            eWout + (size_t)l * 128, eBout + l, simbuf);

        float* ef_out = (l == L - 1) ? (float*)d_out : ef_ws;
        k_edge_update<<<B * N, 128, 0, stream>>>(ef_cur, simbuf, ef_out);
        ef_cur = ef_out;
    }
}